// Round 4
// baseline (299.752 us; speedup 1.0000x reference)
//
#include <hip/hip_runtime.h>
#include <math.h>

// x:    [B=8, C=4, H=256, W=256] f32
// filt: [B, C*25, H, W]          f32
// out:  [B, 1, H, W]             f32
// out[b,h,w] = tanh( sum_{c,p} x_pad[b,c,h+p/5-2, w+p%5-2] * filt[b,c*25+p,h,w] )
//
// Bench model: bench_dur = kernel_dur + ~204us fixed harness fills (confirmed r2/r3).
// Evidence so far: kernel ~72-74us (3.0 TB/s consumed) across {8,16} waves/CU,
// {1,4} KB runs, reg-loads vs async DMA => concurrency- and pattern-insensitive.
// Copy ubench 6.29 TB/s = 3.15 read + 3.15 write; we sit at the read-side rate.
// Last untested lever: the nt flag on filt loads (may block L2/L3 allocation).
// This round = byte-identical r3 structure, nt REMOVED from loads (A/B on nt).
#define Hd 256
#define Wd 256
#define Cc 4
#define KK 5
#define HT 4              // output rows per block (one per wave at reduction)
#define XWR (HT + KK - 1) // 8 x-window rows in registers

typedef float v4f __attribute__((ext_vector_type(4)));

__global__ __launch_bounds__(256, 2) void dynf_kernel(const float* __restrict__ x,
                                                      const float* __restrict__ filt,
                                                      float* __restrict__ out) {
    // 512 blocks; bid&7 = XCD id (HW round-robin). XCD k owns batch k's 64 row
    // tiles => x slice (1MB) L2-resident, disjoint 26MB filt slab per XCD.
    const int bid  = blockIdx.x;
    const int lg   = ((bid & 7) << 6) + (bid >> 3);
    const int b    = lg >> 6;          // batch == XCD id
    const int h0   = (lg & 63) << 2;   // first of 4 output rows
    const int c    = threadIdx.x >> 6; // wave id = channel (wave-uniform)
    const int lane = threadIdx.x & 63;
    const int w0   = lane << 2;

    const size_t HW = (size_t)Hd * Wd;
    const float* xc = x + ((size_t)b * Cc + c) * HW;
    const float* fb = filt + ((size_t)b * (Cc * KK * KK) + (size_t)c * (KK * KK)) * HW
                      + (size_t)h0 * Wd + w0;

    // ---- x window in registers: rows h0-2 .. h0+5, cols w0-2 .. w0+5.
    float xw[XWR][8];
    const v4f vz = {0.f, 0.f, 0.f, 0.f};
#pragma unroll
    for (int ri = 0; ri < XWR; ++ri) {
        const int g = h0 + ri - 2;
        if (g >= 0 && g < Hd) {
            const float* xr = xc + (size_t)g * Wd;
            v4f left  = *(const v4f*)(xr + (w0 ? (w0 - 4) : 0));
            v4f mid   = *(const v4f*)(xr + w0);
            v4f right = *(const v4f*)(xr + ((w0 + 4 < Wd) ? (w0 + 4) : 0));
            if (w0 == 0)      left  = vz;
            if (w0 + 4 >= Wd) right = vz;
            xw[ri][0] = left.z;  xw[ri][1] = left.w;
            xw[ri][2] = mid.x;   xw[ri][3] = mid.y;
            xw[ri][4] = mid.z;   xw[ri][5] = mid.w;
            xw[ri][6] = right.x; xw[ri][7] = right.y;
        } else {
#pragma unroll
            for (int j = 0; j < 8; ++j) xw[ri][j] = 0.f;
        }
    }

    v4f acc[HT];
#pragma unroll
    for (int r = 0; r < HT; ++r) acc[r] = vz;

    // ---- 25 filter planes, 4KB contiguous per wave-plane. PLAIN loads this
    // round (vs r0/r3's nontemporal): let L2/L3 allocate filt normally.
#pragma unroll
    for (int p = 0; p < KK * KK; ++p) {
        const int di = p / KK, dj = p % KK;
        const float* fp = fb + (size_t)p * HW;
#pragma unroll
        for (int r = 0; r < HT; ++r) {
            v4f f = *(const v4f*)(fp + (size_t)r * Wd);
            acc[r].x = fmaf(xw[r + di][0 + dj], f.x, acc[r].x);
            acc[r].y = fmaf(xw[r + di][1 + dj], f.y, acc[r].y);
            acc[r].z = fmaf(xw[r + di][2 + dj], f.z, acc[r].z);
            acc[r].w = fmaf(xw[r + di][3 + dj], f.w, acc[r].w);
        }
    }

    // ---- Cross-wave channel reduction: 16KB LDS, b128 conflict-free.
    __shared__ v4f red[Cc][HT][64];
#pragma unroll
    for (int r = 0; r < HT; ++r) red[c][r][lane] = acc[r];
    __syncthreads();

    // Wave c produces output row h0+c.
    {
        const int r = c;
        v4f s = red[0][r][lane] + red[1][r][lane] + red[2][r][lane] + red[3][r][lane];
        v4f o;
        o.x = tanhf(s.x); o.y = tanhf(s.y); o.z = tanhf(s.z); o.w = tanhf(s.w);
        __builtin_nontemporal_store(o, (v4f*)(out + (size_t)b * HW + (size_t)(h0 + r) * Wd + w0));
    }
}

extern "C" void kernel_launch(void* const* d_in, const int* in_sizes, int n_in,
                              void* d_out, int out_size, void* d_ws, size_t ws_size,
                              hipStream_t stream) {
    const float* x    = (const float*)d_in[0];   // [8,4,256,256]
    const float* filt = (const float*)d_in[1];   // [8,100,256,256]
    float* out        = (float*)d_out;           // [8,1,256,256]

    const int grid  = 512;   // (b, 4-row tile): 8 batches x 64 tiles, 2 blocks/CU
    const int block = 256;   // 4 waves = 4 channels
    dynf_kernel<<<grid, block, 0, stream>>>(x, filt, out);
}

// Round 5
// 275.567 us; speedup vs baseline: 1.0878x; 1.0878x over previous
//
#include <hip/hip_runtime.h>
#include <math.h>

// x:    [B=8, C=4, H=256, W=256] f32
// filt: [B, C*25, H, W]          f32
// out:  [B, 1, H, W]             f32
// out[b,h,w] = tanh( sum_{c,p} x_pad[b,c,h+p/5-2, w+p%5-2] * filt[b,c*25+p,h,w] )
//
// FINAL (restored round-0 best, 274-276us bench = ~72us kernel = 3.0 TB/s).
// Session evidence: occupancy {4,8,16} waves/CU, DRAM run length {1,4,8} KB,
// MLP depth {compiler, 8-deep async DMA}, cache policy {nt, plain, allocating}
// all converge at 72-74us best => read-path ceiling (~3.15 TB/s = read share of
// the 6.29 TB/s bidirectional copy ubench; fills do 6.7 TB/s write-only).
// Mandatory traffic 218 MB => floor ~69us. We are at ~96% of it.
// nt on filt is load-bearing: removing it costs +22us (L1/L2 thrash of x).
#define Hd 256
#define Wd 256
#define Cc 4
#define KK 5

typedef float v4f __attribute__((ext_vector_type(4)));

__global__ __launch_bounds__(256, 4) void dynf_kernel(const float* __restrict__ x,
                                                      const float* __restrict__ filt,
                                                      float* __restrict__ out) {
    // Block = one (b,h) output row. Wave = one input channel c. Lane = 4-pixel group.
    const int bh   = blockIdx.x;            // [0, 2048)
    const int b    = bh >> 8;
    const int h    = bh & 255;
    const int c    = threadIdx.x >> 6;      // wave id = channel
    const int lane = threadIdx.x & 63;
    const int w0   = lane << 2;

    const size_t HW = (size_t)Hd * Wd;
    const float* xc = x + ((size_t)b * Cc + c) * HW;
    const float* fb = filt + ((size_t)(b * (Cc * KK * KK) + c * (KK * KK))) * HW
                      + (size_t)h * Wd + w0;

    float a0 = 0.f, a1 = 0.f, a2 = 0.f, a3 = 0.f;
    const v4f vzero = {0.f, 0.f, 0.f, 0.f};

    #pragma unroll
    for (int di = 0; di < KK; ++di) {
        const int hh = h + di - 2;
        if (hh >= 0 && hh < Hd) {                 // wave-uniform; skips x AND filt loads (×0 anyway)
            const float* xr = xc + (size_t)hh * Wd;
            // x window [w0-2, w0+5] via 3 aligned float4 loads; edge lanes zero-filled.
            v4f left  = *(const v4f*)(xr + (w0 ? (w0 - 4) : 0));
            v4f mid   = *(const v4f*)(xr + w0);
            v4f right = *(const v4f*)(xr + ((w0 + 4 < Wd) ? (w0 + 4) : 0));
            if (w0 == 0)      left  = vzero;
            if (w0 + 4 >= Wd) right = vzero;
            float xrow[8] = {left.z, left.w, mid.x, mid.y, mid.z, mid.w, right.x, right.y};

            const float* fr = fb + (size_t)(di * KK) * HW;
            #pragma unroll
            for (int dj = 0; dj < KK; ++dj) {
                // nontemporal: filt has zero reuse — don't evict x from L1/L2
                v4f f = __builtin_nontemporal_load((const v4f*)(fr + (size_t)dj * HW));
                a0 = fmaf(xrow[dj + 0], f.x, a0);
                a1 = fmaf(xrow[dj + 1], f.y, a1);
                a2 = fmaf(xrow[dj + 2], f.z, a2);
                a3 = fmaf(xrow[dj + 3], f.w, a3);
            }
        }
    }

    // Reduce the 4 channel-waves through LDS (write/read = consecutive b128, conflict-free).
    __shared__ v4f red[Cc][64];
    v4f acc = {a0, a1, a2, a3};
    red[c][lane] = acc;
    __syncthreads();

    if (c == 0) {
        v4f s = red[0][lane] + red[1][lane] + red[2][lane] + red[3][lane];
        v4f o;
        o.x = tanhf(s.x); o.y = tanhf(s.y); o.z = tanhf(s.z); o.w = tanhf(s.w);
        __builtin_nontemporal_store(o, (v4f*)(out + (size_t)b * HW + (size_t)h * Wd + w0));
    }
}

extern "C" void kernel_launch(void* const* d_in, const int* in_sizes, int n_in,
                              void* d_out, int out_size, void* d_ws, size_t ws_size,
                              hipStream_t stream) {
    const float* x    = (const float*)d_in[0];   // [8,4,256,256]
    const float* filt = (const float*)d_in[1];   // [8,100,256,256]
    float* out        = (float*)d_out;           // [8,1,256,256]

    const int grid  = 8 * 256;   // one block per (b,h) row
    const int block = 256;       // 4 waves = 4 channels
    dynf_kernel<<<grid, block, 0, stream>>>(x, filt, out);
}